// Round 1
// baseline (3606.231 us; speedup 1.0000x reference)
//
#include <hip/hip_runtime.h>
#include <hip/hip_bf16.h>

#define T_TOK 4096
#define H_DIM 2048
#define E_EXP 32
#define I_DIM 768
#define K_TOP 8
#define TOTAL_ROWS (T_TOK * K_TOP)   // 32768 (T*K exact)

typedef __attribute__((ext_vector_type(8))) short bfrag;
typedef __attribute__((ext_vector_type(4))) float f32x4;

static __device__ __forceinline__ unsigned short f2bf(float f) {
  unsigned int x = __float_as_uint(f);
  x += 0x7FFFu + ((x >> 16) & 1u);   // round-to-nearest-even
  return (unsigned short)(x >> 16);
}
static __device__ __forceinline__ unsigned int pack2(float a, float b) {
  return (unsigned int)f2bf(a) | ((unsigned int)f2bf(b) << 16);
}

// ---------------- x fp32 -> bf16 ----------------
__global__ __launch_bounds__(256) void cast_x_kernel(const float* __restrict__ x,
                                                     unsigned short* __restrict__ xb) {
  int i = blockIdx.x * 256 + threadIdx.x;      // 8 elems per thread, exact cover
  const float4* s = (const float4*)x;
  float4 a = s[2 * i], b = s[2 * i + 1];
  uint4 o;
  o.x = pack2(a.x, a.y); o.y = pack2(a.z, a.w);
  o.z = pack2(b.x, b.y); o.w = pack2(b.z, b.w);
  ((uint4*)xb)[i] = o;
}

// ---------------- router: fp32 logits, top-8, expert lists ----------------
__global__ __launch_bounds__(256) void router_kernel(
    const float* __restrict__ x, const float* __restrict__ wr,
    float* __restrict__ logits_out, int* __restrict__ tok_list,
    float* __restrict__ wgt_list, int* __restrict__ cnt) {
  __shared__ float xs[4][H_DIM];
  __shared__ float lg[4][E_EXP];
  const int tid = threadIdx.x;
  const int t0 = blockIdx.x * 4;

  const float4* src = (const float4*)(x + (size_t)t0 * H_DIM);
  float4* dst = (float4*)&xs[0][0];
  for (int i = tid; i < 4 * H_DIM / 4; i += 256) dst[i] = src[i];
  __syncthreads();

  const int g = tid >> 3, l8 = tid & 7;        // 32 groups x 8 threads
  float a0 = 0.f, a1 = 0.f, a2 = 0.f, a3 = 0.f;
  const float* w = wr + (size_t)g * H_DIM;
  for (int c = l8; c < H_DIM; c += 8) {
    float wv = w[c];
    a0 += xs[0][c] * wv; a1 += xs[1][c] * wv;
    a2 += xs[2][c] * wv; a3 += xs[3][c] * wv;
  }
  #pragma unroll
  for (int m = 4; m; m >>= 1) {
    a0 += __shfl_xor(a0, m); a1 += __shfl_xor(a1, m);
    a2 += __shfl_xor(a2, m); a3 += __shfl_xor(a3, m);
  }
  if (l8 == 0) { lg[0][g] = a0; lg[1][g] = a1; lg[2][g] = a2; lg[3][g] = a3; }
  __syncthreads();

  if (tid < 128) {                              // coalesced logits output
    int r = tid >> 5, e = tid & 31;
    logits_out[(size_t)(t0 + r) * E_EXP + e] = lg[r][e];
  }

  if (tid < 4) {                                // serial top-8 per token
    int t = t0 + tid;
    unsigned sel = 0;
    float lv[K_TOP]; int ei[K_TOP];
    #pragma unroll
    for (int k = 0; k < K_TOP; ++k) {
      float best = -3.4e38f; int bi = 0;
      for (int e = 0; e < E_EXP; ++e) {
        float v = lg[tid][e];
        if (!((sel >> e) & 1u) && v > best) { best = v; bi = e; }  // ties -> lower idx (stable, matches top_k)
      }
      sel |= 1u << bi; lv[k] = best; ei[k] = bi;
    }
    float m = lv[0], se = 0.f, ex[K_TOP];
    #pragma unroll
    for (int k = 0; k < K_TOP; ++k) { ex[k] = __expf(lv[k] - m); se += ex[k]; }
    float inv = 1.f / se;                       // softmax denom cancels in topk_w/sum(topk_w)
    #pragma unroll
    for (int k = 0; k < K_TOP; ++k) {
      int e = ei[k];
      int pos = atomicAdd(&cnt[e], 1);
      tok_list[e * T_TOK + pos] = t;
      wgt_list[e * T_TOK + pos] = ex[k] * inv;
    }
  }
}

// ---------------- exclusive scan of expert counts ----------------
__global__ void scan_kernel(const int* __restrict__ cnt, int* __restrict__ aoff) {
  if (threadIdx.x == 0 && blockIdx.x == 0) {
    int s = 0;
    for (int e = 0; e < E_EXP; ++e) { aoff[e] = s; s += cnt[e]; }
  }
}

// ---------------- gate+up fused GEMM, silu*up*w -> act (bf16) ----------------
__global__ __launch_bounds__(256) void gateup_kernel(
    const unsigned short* __restrict__ xb,
    const float* __restrict__ wg, const float* __restrict__ wu,
    const int* __restrict__ cnt, const int* __restrict__ aoff,
    const int* __restrict__ tok_list, const float* __restrict__ wgt_list,
    unsigned short* __restrict__ act) {
  const int e = blockIdx.x >> 5;
  const int rb = blockIdx.x & 31;
  const int nt = cnt[e];
  const int row0 = rb * 128;
  if (row0 >= nt) return;
  const int n0 = blockIdx.y * 128;

  __shared__ __align__(16) unsigned short As[128 * 64];
  __shared__ __align__(16) unsigned short Bgs[128 * 64];
  __shared__ __align__(16) unsigned short Bus[128 * 64];
  __shared__ int toks[128];
  __shared__ float wrow[128];

  const int tid = threadIdx.x;
  if (tid < 128) {
    int r = row0 + tid;
    bool v = r < nt;
    toks[tid] = v ? tok_list[e * T_TOK + r] : 0;
    wrow[tid] = v ? wgt_list[e * T_TOK + r] : 0.f;
  }

  f32x4 zero = {0.f, 0.f, 0.f, 0.f};
  f32x4 ag[4][4], au[4][4];
  #pragma unroll
  for (int m = 0; m < 4; ++m)
    #pragma unroll
    for (int n = 0; n < 4; ++n) { ag[m][n] = zero; au[m][n] = zero; }

  const int lane = tid & 63;
  const int wv = tid >> 6;
  const int wr = (wv >> 1) * 64;
  const int wc = (wv & 1) * 64;

  const float* wgp = wg + ((size_t)e * I_DIM + n0) * H_DIM;
  const float* wup = wu + ((size_t)e * I_DIM + n0) * H_DIM;

  for (int kt = 0; kt < H_DIM; kt += 64) {
    __syncthreads();
    // stage A (gathered x rows, bf16, XOR-swizzled vs 128B-stride conflicts)
    #pragma unroll
    for (int i = 0; i < 4; ++i) {
      int q = tid + 256 * i;
      int r = q >> 3, cc = q & 7;
      uint4 av = *(const uint4*)(xb + (size_t)toks[r] * H_DIM + (kt + cc * 8));
      int el = (r * 64 + cc * 8) ^ ((r & 7) << 3);
      *(uint4*)&As[el] = av;
    }
    // stage B gate+up (fp32 -> bf16 inline)
    #pragma unroll
    for (int i = 0; i < 4; ++i) {
      int q = tid + 256 * i;
      int r = q >> 3, cc = q & 7;
      size_t off = (size_t)r * H_DIM + (kt + cc * 8);
      float4 g0 = *(const float4*)(wgp + off);
      float4 g1 = *(const float4*)(wgp + off + 4);
      float4 u0 = *(const float4*)(wup + off);
      float4 u1 = *(const float4*)(wup + off + 4);
      int el = (r * 64 + cc * 8) ^ ((r & 7) << 3);
      uint4 pg, pu;
      pg.x = pack2(g0.x, g0.y); pg.y = pack2(g0.z, g0.w);
      pg.z = pack2(g1.x, g1.y); pg.w = pack2(g1.z, g1.w);
      pu.x = pack2(u0.x, u0.y); pu.y = pack2(u0.z, u0.w);
      pu.z = pack2(u1.x, u1.y); pu.w = pack2(u1.z, u1.w);
      *(uint4*)&Bgs[el] = pg;
      *(uint4*)&Bus[el] = pu;
    }
    __syncthreads();
    #pragma unroll
    for (int kk = 0; kk < 2; ++kk) {
      bfrag a[4], bg[4], bu[4];
      #pragma unroll
      for (int m = 0; m < 4; ++m) {
        int r = wr + m * 16 + (lane & 15);
        int el = (r * 64 + kk * 32 + (lane >> 4) * 8) ^ ((r & 7) << 3);
        a[m] = *(const bfrag*)&As[el];
      }
      #pragma unroll
      for (int n = 0; n < 4; ++n) {
        int r = wc + n * 16 + (lane & 15);
        int el = (r * 64 + kk * 32 + (lane >> 4) * 8) ^ ((r & 7) << 3);
        bg[n] = *(const bfrag*)&Bgs[el];
        bu[n] = *(const bfrag*)&Bus[el];
      }
      #pragma unroll
      for (int m = 0; m < 4; ++m)
        #pragma unroll
        for (int n = 0; n < 4; ++n) {
          ag[m][n] = __builtin_amdgcn_mfma_f32_16x16x32_bf16(a[m], bg[n], ag[m][n], 0, 0, 0);
          au[m][n] = __builtin_amdgcn_mfma_f32_16x16x32_bf16(a[m], bu[n], au[m][n], 0, 0, 0);
        }
    }
  }

  const int aoe = aoff[e];
  #pragma unroll
  for (int m = 0; m < 4; ++m) {
    #pragma unroll
    for (int r = 0; r < 4; ++r) {
      int rloc = wr + m * 16 + (lane >> 4) * 4 + r;   // D: row=(lane>>4)*4+r, col=lane&15
      int grow = row0 + rloc;
      if (grow < nt) {
        float w = wrow[rloc];
        size_t base = (size_t)(aoe + grow) * I_DIM + n0 + wc + (lane & 15);
        #pragma unroll
        for (int n = 0; n < 4; ++n) {
          float g = ag[m][n][r];
          float u = au[m][n][r];
          float s = g / (1.f + __expf(-g));           // silu
          act[base + n * 16] = f2bf(s * u * w);       // routing weight folded here
        }
      }
    }
  }
}

// ---------------- down GEMM + atomic scatter into out ----------------
__global__ __launch_bounds__(256) void down_kernel(
    const unsigned short* __restrict__ act, const float* __restrict__ wd,
    const int* __restrict__ cnt, const int* __restrict__ aoff,
    const int* __restrict__ tok_list, float* __restrict__ out) {
  const int e = blockIdx.x >> 5;
  const int rb = blockIdx.x & 31;
  const int nt = cnt[e];
  const int row0 = rb * 128;
  if (row0 >= nt) return;
  const int h0 = blockIdx.y * 128;

  __shared__ __align__(16) unsigned short As[128 * 64];
  __shared__ __align__(16) unsigned short Bd[128 * 64];
  __shared__ int toks[128];

  const int tid = threadIdx.x;
  const int aoe = aoff[e];
  if (tid < 128) {
    int r = row0 + tid;
    toks[tid] = (r < nt) ? tok_list[e * T_TOK + r] : 0;
  }

  f32x4 zero = {0.f, 0.f, 0.f, 0.f};
  f32x4 acc[4][4];
  #pragma unroll
  for (int m = 0; m < 4; ++m)
    #pragma unroll
    for (int n = 0; n < 4; ++n) acc[m][n] = zero;

  const int lane = tid & 63;
  const int wv = tid >> 6;
  const int wr = (wv >> 1) * 64;
  const int wc = (wv & 1) * 64;

  const float* wdp = wd + ((size_t)e * H_DIM + h0) * I_DIM;

  for (int kt = 0; kt < I_DIM; kt += 64) {
    __syncthreads();
    #pragma unroll
    for (int i = 0; i < 4; ++i) {
      int q = tid + 256 * i;
      int r = q >> 3, cc = q & 7;
      int arow = aoe + row0 + r;
      if (arow > TOTAL_ROWS - 1) arow = TOTAL_ROWS - 1;  // clamp: stay in act buffer (masked later)
      uint4 av = *(const uint4*)(act + (size_t)arow * I_DIM + (kt + cc * 8));
      int el = (r * 64 + cc * 8) ^ ((r & 7) << 3);
      *(uint4*)&As[el] = av;
    }
    #pragma unroll
    for (int i = 0; i < 4; ++i) {
      int q = tid + 256 * i;
      int r = q >> 3, cc = q & 7;
      size_t off = (size_t)r * I_DIM + (kt + cc * 8);
      float4 b0 = *(const float4*)(wdp + off);
      float4 b1 = *(const float4*)(wdp + off + 4);
      int el = (r * 64 + cc * 8) ^ ((r & 7) << 3);
      uint4 pb;
      pb.x = pack2(b0.x, b0.y); pb.y = pack2(b0.z, b0.w);
      pb.z = pack2(b1.x, b1.y); pb.w = pack2(b1.z, b1.w);
      *(uint4*)&Bd[el] = pb;
    }
    __syncthreads();
    #pragma unroll
    for (int kk = 0; kk < 2; ++kk) {
      bfrag a[4], b[4];
      #pragma unroll
      for (int m = 0; m < 4; ++m) {
        int r = wr + m * 16 + (lane & 15);
        int el = (r * 64 + kk * 32 + (lane >> 4) * 8) ^ ((r & 7) << 3);
        a[m] = *(const bfrag*)&As[el];
      }
      #pragma unroll
      for (int n = 0; n < 4; ++n) {
        int r = wc + n * 16 + (lane & 15);
        int el = (r * 64 + kk * 32 + (lane >> 4) * 8) ^ ((r & 7) << 3);
        b[n] = *(const bfrag*)&Bd[el];
      }
      #pragma unroll
      for (int m = 0; m < 4; ++m)
        #pragma unroll
        for (int n = 0; n < 4; ++n)
          acc[m][n] = __builtin_amdgcn_mfma_f32_16x16x32_bf16(a[m], b[n], acc[m][n], 0, 0, 0);
    }
  }

  #pragma unroll
  for (int m = 0; m < 4; ++m) {
    #pragma unroll
    for (int r = 0; r < 4; ++r) {
      int rloc = wr + m * 16 + (lane >> 4) * 4 + r;
      int grow = row0 + rloc;
      if (grow < nt) {
        int tok = toks[rloc];
        size_t base = (size_t)tok * H_DIM + h0 + wc + (lane & 15);
        #pragma unroll
        for (int n = 0; n < 4; ++n)
          atomicAdd(out + base + n * 16, acc[m][n][r]);
      }
    }
  }
}

// ---------------- launch ----------------
extern "C" void kernel_launch(void* const* d_in, const int* in_sizes, int n_in,
                              void* d_out, int out_size, void* d_ws, size_t ws_size,
                              hipStream_t stream) {
  const float* x  = (const float*)d_in[0];
  const float* wr = (const float*)d_in[1];
  const float* wg = (const float*)d_in[2];
  const float* wu = (const float*)d_in[3];
  const float* wd = (const float*)d_in[4];
  float* out = (float*)d_out;
  float* logits_out = out + (size_t)T_TOK * H_DIM;   // tuple order: (out, router_logits)

  // workspace layout (68.2 MB total)
  char* ws = (char*)d_ws;
  unsigned short* xb   = (unsigned short*)ws;                              // 16 MiB
  int*   tok_list      = (int*)(ws + 16777216);                            // 512 KiB
  float* wgt_list      = (float*)(ws + 16777216 + 524288);                 // 512 KiB
  int*   cnt           = (int*)(ws + 16777216 + 1048576);                  // 128 B
  int*   aoff          = (int*)(ws + 16777216 + 1048576 + 256);            // 128 B
  unsigned short* act  = (unsigned short*)(ws + 16777216 + 1048576 + 512); // 50.3 MiB

  hipMemsetAsync(cnt, 0, 256, stream);
  hipMemsetAsync(out, 0, (size_t)T_TOK * H_DIM * sizeof(float), stream);

  cast_x_kernel<<<(T_TOK * H_DIM) / (256 * 8), 256, 0, stream>>>(x, xb);
  router_kernel<<<T_TOK / 4, 256, 0, stream>>>(x, wr, logits_out, tok_list, wgt_list, cnt);
  scan_kernel<<<1, 64, 0, stream>>>(cnt, aoff);
  gateup_kernel<<<dim3(E_EXP * 32, I_DIM / 128), 256, 0, stream>>>(
      xb, wg, wu, cnt, aoff, tok_list, wgt_list, act);
  down_kernel<<<dim3(E_EXP * 32, H_DIM / 128), 256, 0, stream>>>(
      act, wd, cnt, aoff, tok_list, out);
}

// Round 7
// 1483.123 us; speedup vs baseline: 2.4315x; 2.4315x over previous
//
#include <hip/hip_runtime.h>
#include <hip/hip_bf16.h>

#define T_TOK 4096
#define H_DIM 2048
#define E_EXP 32
#define I_DIM 768
#define K_TOP 8
#define TOTAL_ROWS (T_TOK * K_TOP)   // 32768

typedef __attribute__((ext_vector_type(8))) short bfrag;
typedef __attribute__((ext_vector_type(4))) float f32x4;

static __device__ __forceinline__ unsigned short f2bf(float f) {
  unsigned int x = __float_as_uint(f);
  x += 0x7FFFu + ((x >> 16) & 1u);   // round-to-nearest-even
  return (unsigned short)(x >> 16);
}
static __device__ __forceinline__ unsigned int pack2(float a, float b) {
  return (unsigned int)f2bf(a) | ((unsigned int)f2bf(b) << 16);
}

// ---- async global->LDS, 16B per lane, dest = wave-uniform base + lane*16 ----
#if __has_builtin(__builtin_amdgcn_global_load_lds)
typedef __attribute__((address_space(1))) const unsigned int as1_u32;
typedef __attribute__((address_space(3))) unsigned int as3_u32;
static __device__ __forceinline__ void gll16(const unsigned short* g, unsigned short* l) {
  __builtin_amdgcn_global_load_lds((as1_u32*)g, (as3_u32*)l, 16, 0, 0);
}
#else
static __device__ __forceinline__ void gll16(const unsigned short* g, unsigned short* l) {
  uint4 v = *(const uint4*)g;                       // emulation: same layout
  ((uint4*)l)[threadIdx.x & 63] = v;
}
#endif

// ---------------- fp32 -> bf16 bulk cast (x and weights) ----------------
__global__ __launch_bounds__(256) void cast_f32_bf16_kernel(const float* __restrict__ s,
                                                            unsigned short* __restrict__ d,
                                                            long long n8) {
  long long i = (long long)blockIdx.x * 256 + threadIdx.x;   // 8 elems per thread
  if (i >= n8) return;
  const float4* sp = (const float4*)s;
  float4 a = sp[2 * i], b = sp[2 * i + 1];
  uint4 o;
  o.x = pack2(a.x, a.y); o.y = pack2(a.z, a.w);
  o.z = pack2(b.x, b.y); o.w = pack2(b.z, b.w);
  ((uint4*)d)[i] = o;
}

// ---------------- router: fp32 logits, top-8, expert lists ----------------
__global__ __launch_bounds__(256) void router_kernel(
    const float* __restrict__ x, const float* __restrict__ wr,
    float* __restrict__ logits_out, int* __restrict__ tok_list,
    float* __restrict__ wgt_list, int* __restrict__ cnt) {
  __shared__ float xs[4][H_DIM];
  __shared__ float lg[4][E_EXP];
  const int tid = threadIdx.x;
  const int t0 = blockIdx.x * 4;

  const float4* src = (const float4*)(x + (size_t)t0 * H_DIM);
  float4* dst = (float4*)&xs[0][0];
  for (int i = tid; i < 4 * H_DIM / 4; i += 256) dst[i] = src[i];
  __syncthreads();

  const int g = tid >> 3, l8 = tid & 7;        // 32 groups x 8 threads
  float a0 = 0.f, a1 = 0.f, a2 = 0.f, a3 = 0.f;
  const float* w = wr + (size_t)g * H_DIM;
  for (int c = l8; c < H_DIM; c += 8) {
    float wv = w[c];
    a0 += xs[0][c] * wv; a1 += xs[1][c] * wv;
    a2 += xs[2][c] * wv; a3 += xs[3][c] * wv;
  }
  #pragma unroll
  for (int m = 4; m; m >>= 1) {
    a0 += __shfl_xor(a0, m); a1 += __shfl_xor(a1, m);
    a2 += __shfl_xor(a2, m); a3 += __shfl_xor(a3, m);
  }
  if (l8 == 0) { lg[0][g] = a0; lg[1][g] = a1; lg[2][g] = a2; lg[3][g] = a3; }
  __syncthreads();

  if (tid < 128) {
    int r = tid >> 5, e = tid & 31;
    logits_out[(size_t)(t0 + r) * E_EXP + e] = lg[r][e];
  }

  if (tid < 4) {                                // serial top-8 per token
    int t = t0 + tid;
    unsigned sel = 0;
    float lv[K_TOP]; int ei[K_TOP];
    #pragma unroll
    for (int k = 0; k < K_TOP; ++k) {
      float best = -3.4e38f; int bi = 0;
      for (int e = 0; e < E_EXP; ++e) {
        float v = lg[tid][e];
        if (!((sel >> e) & 1u) && v > best) { best = v; bi = e; }
      }
      sel |= 1u << bi; lv[k] = best; ei[k] = bi;
    }
    float m = lv[0], se = 0.f, ex[K_TOP];
    #pragma unroll
    for (int k = 0; k < K_TOP; ++k) { ex[k] = __expf(lv[k] - m); se += ex[k]; }
    float inv = 1.f / se;                       // softmax denom cancels in topk_w/sum
    #pragma unroll
    for (int k = 0; k < K_TOP; ++k) {
      int e = ei[k];
      int pos = atomicAdd(&cnt[e], 1);
      tok_list[e * T_TOK + pos] = t;
      wgt_list[e * T_TOK + pos] = ex[k] * inv;
    }
  }
}

__global__ void scan_kernel(const int* __restrict__ cnt, int* __restrict__ aoff) {
  if (threadIdx.x == 0 && blockIdx.x == 0) {
    int s = 0;
    for (int e = 0; e < E_EXP; ++e) { aoff[e] = s; s += cnt[e]; }
  }
}

// ================= OPTIMIZED PATH (bf16 weights precast in ws) =================
// m97-style: global_load_lds staging (linear LDS dest, inverse-swizzled global
// source), 2 barriers/K-step, swizzled ds_read_b128 fragment reads.

// gate+up fused GEMM -> act bf16.  BM=128 BN=128 BK=64, 256 thr (4 waves 2x2).
__global__ __launch_bounds__(256) void gateup_kernel(
    const unsigned short* __restrict__ xb,
    const unsigned short* __restrict__ wgb, const unsigned short* __restrict__ wub,
    const int* __restrict__ cnt, const int* __restrict__ aoff,
    const int* __restrict__ tok_list, const float* __restrict__ wgt_list,
    unsigned short* __restrict__ act) {
  const int bx = blockIdx.x;
  const int cb = bx % 6;            // col-block innermost: expert locality in L2/L3
  const int t  = bx / 6;
  const int e  = t >> 5, rb = t & 31;
  const int nt = cnt[e];
  const int row0 = rb * 128;
  if (row0 >= nt) return;
  const int n0 = cb * 128;

  __shared__ __align__(16) unsigned short As[128 * 64];
  __shared__ __align__(16) unsigned short Bgs[128 * 64];
  __shared__ __align__(16) unsigned short Bus[128 * 64];
  __shared__ int toks[128];
  __shared__ float wrow[128];

  const int tid = threadIdx.x;
  if (tid < 128) {
    int r = row0 + tid;
    bool v = r < nt;
    toks[tid] = v ? tok_list[e * T_TOK + r] : 0;
    wrow[tid] = v ? wgt_list[e * T_TOK + r] : 0.f;
  }
  __syncthreads();

  // staging geometry: call j covers LDS rows j*32..j*32+31; this thread serves
  // row r=j*32+(tid>>3).  Linear LDS slot o = j*2048 + tid*8 holds (r, c) with
  // c = 8*((tid&7) ^ (r&7))  -> pre-swizzle the SOURCE column (rule #21).
  const int rr = tid >> 3, c8 = tid & 7;
  const unsigned short* pa[4];
  const unsigned short* pbg[4];
  #pragma unroll
  for (int j = 0; j < 4; ++j) {
    int r = j * 32 + rr;
    int c = 8 * (c8 ^ (r & 7));
    pa[j]  = xb + (size_t)toks[r] * H_DIM + c;
    pbg[j] = wgb + ((size_t)e * I_DIM + n0 + r) * H_DIM + c;
  }
  const size_t du = (size_t)(wub - wgb);   // uniform gate->up offset (elements)

  f32x4 zero = {0.f, 0.f, 0.f, 0.f};
  f32x4 ag[4][4], au[4][4];
  #pragma unroll
  for (int m = 0; m < 4; ++m)
    #pragma unroll
    for (int n = 0; n < 4; ++n) { ag[m][n] = zero; au[m][n] = zero; }

  const int lane = tid & 63;
  const int w = tid >> 6;
  const int wr = (w >> 1) * 64, wc = (w & 1) * 64;
  const int lbase = w * 512;               // wave-uniform LDS element offset

  for (int kt = 0; kt < H_DIM; kt += 64) {
    #pragma unroll
    for (int j = 0; j < 4; ++j) gll16(pa[j] + kt,       &As[j * 2048 + lbase]);
    #pragma unroll
    for (int j = 0; j < 4; ++j) gll16(pbg[j] + kt,      &Bgs[j * 2048 + lbase]);
    #pragma unroll
    for (int j = 0; j < 4; ++j) gll16(pbg[j] + du + kt, &Bus[j * 2048 + lbase]);
    __syncthreads();                       // drains vmcnt -> tiles visible
    #pragma unroll
    for (int kk = 0; kk < 2; ++kk) {
      bfrag a[4], bg[4], bu[4];
      #pragma unroll
      for (int m = 0; m < 4; ++m) {
        int r = wr + m * 16 + (lane & 15);
        int el = (r * 64 + kk * 32 + (lane >> 4) * 8) ^ ((r & 7) << 3);
        a[m] = *(const bfrag*)&As[el];
      }
      #pragma unroll
      for (int n = 0; n < 4; ++n) {
        int r = wc + n * 16 + (lane & 15);
        int el = (r * 64 + kk * 32 + (lane >> 4) * 8) ^ ((r & 7) << 3);
        bg[n] = *(const bfrag*)&Bgs[el];
        bu[n] = *(const bfrag*)&Bus[el];
      }
      #pragma unroll
      for (int m = 0; m < 4; ++m)
        #pragma unroll
        for (int n = 0; n < 4; ++n) {
          ag[m][n] = __builtin_amdgcn_mfma_f32_16x16x32_bf16(a[m], bg[n], ag[m][n], 0, 0, 0);
          au[m][n] = __builtin_amdgcn_mfma_f32_16x16x32_bf16(a[m], bu[n], au[m][n], 0, 0, 0);
        }
    }
    __syncthreads();                       // all reads done before next overwrite
  }

  const int aoe = aoff[e];
  #pragma unroll
  for (int m = 0; m < 4; ++m) {
    #pragma unroll
    for (int r4 = 0; r4 < 4; ++r4) {
      int rloc = wr + m * 16 + (lane >> 4) * 4 + r4;
      int grow = row0 + rloc;
      if (grow < nt) {
        float wgt = wrow[rloc];
        size_t base = (size_t)(aoe + grow) * I_DIM + n0 + wc + (lane & 15);
        #pragma unroll
        for (int n = 0; n < 4; ++n) {
          float g = ag[m][n][r4], u = au[m][n][r4];
          float s = g / (1.f + __expf(-g));
          act[base + n * 16] = f2bf(s * u * wgt);
        }
      }
    }
  }
}

// down GEMM + atomic scatter.  BM=128 BN=128 BK=64, K=768.
__global__ __launch_bounds__(256) void down_kernel(
    const unsigned short* __restrict__ act, const unsigned short* __restrict__ wdb,
    const int* __restrict__ cnt, const int* __restrict__ aoff,
    const int* __restrict__ tok_list, float* __restrict__ out) {
  const int bx = blockIdx.x;
  const int cb = bx & 15;                  // H col-block innermost
  const int t  = bx >> 4;
  const int e  = t >> 5, rb = t & 31;
  const int nt = cnt[e];
  const int row0 = rb * 128;
  if (row0 >= nt) return;
  const int h0 = cb * 128;

  __shared__ __align__(16) unsigned short As[128 * 64];
  __shared__ __align__(16) unsigned short Bd[128 * 64];
  __shared__ int toks[128];

  const int tid = threadIdx.x;
  const int aoe = aoff[e];
  if (tid < 128) {
    int r = row0 + tid;
    toks[tid] = (r < nt) ? tok_list[e * T_TOK + r] : 0;
  }
  __syncthreads();

  const int rr = tid >> 3, c8 = tid & 7;
  const unsigned short* pa[4];
  const unsigned short* pb[4];
  #pragma unroll
  for (int j = 0; j < 4; ++j) {
    int r = j * 32 + rr;
    int c = 8 * (c8 ^ (r & 7));
    int arow = aoe + row0 + r;
    if (arow > TOTAL_ROWS - 1) arow = TOTAL_ROWS - 1;   // masked at write
    pa[j] = act + (size_t)arow * I_DIM + c;
    pb[j] = wdb + ((size_t)e * H_DIM + h0 + r) * I_DIM + c;
  }

  f32x4 zero = {0.f, 0.f, 0.f, 0.f};
  f32x4 acc[4][4];
  #pragma unroll
  for (int m = 0; m < 4; ++m)
    #pragma unroll
    for (int n = 0; n < 4; ++n) acc[m][n] = zero;

  const int lane = tid & 63;
  const int w = tid >> 6;
  const int wr = (w >> 1) * 64, wc = (w & 1) * 64;
  const int lbase = w * 512;

  for (int kt = 0; kt < I_DIM; kt += 64) {
    #pragma unroll
    for (int j = 0; j < 4; ++j) gll16(pa[j] + kt, &As[j * 2048 + lbase]);
    #pragma unroll
    for (int j = 0; j < 4; ++j) gll16(pb[j] + kt, &Bd[j * 2048 + lbase]);
    __syncthreads();
    #pragma unroll
    for (int kk = 0; kk < 2; ++kk) {
      bfrag a[4], b[4];
      #pragma unroll
      for (int m = 0; m < 4; ++m) {
        int r = wr + m * 16 + (lane & 15);
        int el = (r * 64 + kk * 32 + (lane >> 4) * 8) ^ ((r & 7) << 3);
        a[m] = *(const bfrag*)&As[el];
      }
      #pragma unroll
      for (int n = 0; n < 4; ++n) {
        int r = wc + n * 16 + (lane & 15);
        int el = (r * 64 + kk * 32 + (lane >> 4) * 8) ^ ((r & 7) << 3);
        b[n] = *(const bfrag*)&Bd[el];
      }
      #pragma unroll
      for (int m = 0; m < 4; ++m)
        #pragma unroll
        for (int n = 0; n < 4; ++n)
          acc[m][n] = __builtin_amdgcn_mfma_f32_16x16x32_bf16(a[m], b[n], acc[m][n], 0, 0, 0);
    }
    __syncthreads();
  }

  #pragma unroll
  for (int m = 0; m < 4; ++m) {
    #pragma unroll
    for (int r4 = 0; r4 < 4; ++r4) {
      int rloc = wr + m * 16 + (lane >> 4) * 4 + r4;
      int grow = row0 + rloc;
      if (grow < nt) {
        int tok = toks[rloc];
        size_t base = (size_t)tok * H_DIM + h0 + wc + (lane & 15);
        #pragma unroll
        for (int n = 0; n < 4; ++n)
          atomicAdd(out + base + n * 16, acc[m][n][r4]);
      }
    }
  }
}

// ================= FALLBACK PATH (round-1, used only if ws too small) =========
__global__ __launch_bounds__(256) void gateup_fb(
    const unsigned short* __restrict__ xb,
    const float* __restrict__ wg, const float* __restrict__ wu,
    const int* __restrict__ cnt, const int* __restrict__ aoff,
    const int* __restrict__ tok_list, const float* __restrict__ wgt_list,
    unsigned short* __restrict__ act) {
  const int e = blockIdx.x >> 5;
  const int rb = blockIdx.x & 31;
  const int nt = cnt[e];
  const int row0 = rb * 128;
  if (row0 >= nt) return;
  const int n0 = blockIdx.y * 128;

  __shared__ __align__(16) unsigned short As[128 * 64];
  __shared__ __align__(16) unsigned short Bgs[128 * 64];
  __shared__ __align__(16) unsigned short Bus[128 * 64];
  __shared__ int toks[128];
  __shared__ float wrow[128];

  const int tid = threadIdx.x;
  if (tid < 128) {
    int r = row0 + tid;
    bool v = r < nt;
    toks[tid] = v ? tok_list[e * T_TOK + r] : 0;
    wrow[tid] = v ? wgt_list[e * T_TOK + r] : 0.f;
  }

  f32x4 zero = {0.f, 0.f, 0.f, 0.f};
  f32x4 ag[4][4], au[4][4];
  #pragma unroll
  for (int m = 0; m < 4; ++m)
    #pragma unroll
    for (int n = 0; n < 4; ++n) { ag[m][n] = zero; au[m][n] = zero; }

  const int lane = tid & 63;
  const int wv = tid >> 6;
  const int wr = (wv >> 1) * 64;
  const int wc = (wv & 1) * 64;

  const float* wgp = wg + ((size_t)e * I_DIM + n0) * H_DIM;
  const float* wup = wu + ((size_t)e * I_DIM + n0) * H_DIM;

  for (int kt = 0; kt < H_DIM; kt += 64) {
    __syncthreads();
    #pragma unroll
    for (int i = 0; i < 4; ++i) {
      int q = tid + 256 * i;
      int r = q >> 3, cc = q & 7;
      uint4 av = *(const uint4*)(xb + (size_t)toks[r] * H_DIM + (kt + cc * 8));
      int el = (r * 64 + cc * 8) ^ ((r & 7) << 3);
      *(uint4*)&As[el] = av;
    }
    #pragma unroll
    for (int i = 0; i < 4; ++i) {
      int q = tid + 256 * i;
      int r = q >> 3, cc = q & 7;
      size_t off = (size_t)r * H_DIM + (kt + cc * 8);
      float4 g0 = *(const float4*)(wgp + off);
      float4 g1 = *(const float4*)(wgp + off + 4);
      float4 u0 = *(const float4*)(wup + off);
      float4 u1 = *(const float4*)(wup + off + 4);
      int el = (r * 64 + cc * 8) ^ ((r & 7) << 3);
      uint4 pg, pu;
      pg.x = pack2(g0.x, g0.y); pg.y = pack2(g0.z, g0.w);
      pg.z = pack2(g1.x, g1.y); pg.w = pack2(g1.z, g1.w);
      pu.x = pack2(u0.x, u0.y); pu.y = pack2(u0.z, u0.w);
      pu.z = pack2(u1.x, u1.y); pu.w = pack2(u1.z, u1.w);
      *(uint4*)&Bgs[el] = pg;
      *(uint4*)&Bus[el] = pu;
    }
    __syncthreads();
    #pragma unroll
    for (int kk = 0; kk < 2; ++kk) {
      bfrag a[4], bg[4], bu[4];
      #pragma unroll
      for (int m = 0; m < 4; ++m) {
        int r = wr + m * 16 + (lane & 15);
        int el = (r * 64 + kk * 32 + (lane >> 4) * 8) ^ ((r & 7) << 3);
        a[m] = *(const bfrag*)&As[el];
      }
      #pragma unroll
      for (int n = 0; n < 4; ++n) {
        int r = wc + n * 16 + (lane & 15);
        int el = (r * 64 + kk * 32 + (lane >> 4) * 8) ^ ((r & 7) << 3);
        bg[n] = *(const bfrag*)&Bgs[el];
        bu[n] = *(const bfrag*)&Bus[el];
      }
      #pragma unroll
      for (int m = 0; m < 4; ++m)
        #pragma unroll
        for (int n = 0; n < 4; ++n) {
          ag[m][n] = __builtin_amdgcn_mfma_f32_16x16x32_bf16(a[m], bg[n], ag[m][n], 0, 0, 0);
          au[m][n] = __builtin_amdgcn_mfma_f32_16x16x32_bf16(a[m], bu[n], au[m][n], 0, 0, 0);
        }
    }
  }

  const int aoe = aoff[e];
  #pragma unroll
  for (int m = 0; m < 4; ++m) {
    #pragma unroll
    for (int r4 = 0; r4 < 4; ++r4) {
      int rloc = wr + m * 16 + (lane >> 4) * 4 + r4;
      int grow = row0 + rloc;
      if (grow < nt) {
        float wgt = wrow[rloc];
        size_t base = (size_t)(aoe + grow) * I_DIM + n0 + wc + (lane & 15);
        #pragma unroll
        for (int n = 0; n < 4; ++n) {
          float g = ag[m][n][r4];
          float u = au[m][n][r4];
          float s = g / (1.f + __expf(-g));
          act[base + n * 16] = f2bf(s * u * wgt);
        }
      }
    }
  }
}

__global__ __launch_bounds__(256) void down_fb(
    const unsigned short* __restrict__ act, const float* __restrict__ wd,
    const int* __restrict__ cnt, const int* __restrict__ aoff,
    const int* __restrict__ tok_list, float* __restrict__ out) {
  const int e = blockIdx.x >> 5;
  const int rb = blockIdx.x & 31;
  const int nt = cnt[e];
  const int row0 = rb * 128;
  if (row0 >= nt) return;
  const int h0 = blockIdx.y * 128;

  __shared__ __align__(16) unsigned short As[128 * 64];
  __shared__ __align__(16) unsigned short Bd[128 * 64];
  __shared__ int toks[128];

  const int tid = threadIdx.x;
  const int aoe = aoff[e];
  if (tid < 128) {
    int r = row0 + tid;
    toks[tid] = (r < nt) ? tok_list[e * T_TOK + r] : 0;
  }

  f32x4 zero = {0.f, 0.f, 0.f, 0.f};
  f32x4 acc[4][4];
  #pragma unroll
  for (int m = 0; m < 4; ++m)
    #pragma unroll
    for (int n = 0; n < 4; ++n) acc[m][n] = zero;

  const int lane = tid & 63;
  const int wv = tid >> 6;
  const int wr = (wv >> 1) * 64;
  const int wc = (wv & 1) * 64;

  const float* wdp = wd + ((size_t)e * H_DIM + h0) * I_DIM;

  for (int kt = 0; kt < I_DIM; kt += 64) {
    __syncthreads();
    #pragma unroll
    for (int i = 0; i < 4; ++i) {
      int q = tid + 256 * i;
      int r = q >> 3, cc = q & 7;
      int arow = aoe + row0 + r;
      if (arow > TOTAL_ROWS - 1) arow = TOTAL_ROWS - 1;
      uint4 av = *(const uint4*)(act + (size_t)arow * I_DIM + (kt + cc * 8));
      int el = (r * 64 + cc * 8) ^ ((r & 7) << 3);
      *(uint4*)&As[el] = av;
    }
    #pragma unroll
    for (int i = 0; i < 4; ++i) {
      int q = tid + 256 * i;
      int r = q >> 3, cc = q & 7;
      size_t off = (size_t)r * I_DIM + (kt + cc * 8);
      float4 b0 = *(const float4*)(wdp + off);
      float4 b1 = *(const float4*)(wdp + off + 4);
      int el = (r * 64 + cc * 8) ^ ((r & 7) << 3);
      uint4 pb;
      pb.x = pack2(b0.x, b0.y); pb.y = pack2(b0.z, b0.w);
      pb.z = pack2(b1.x, b1.y); pb.w = pack2(b1.z, b1.w);
      *(uint4*)&Bd[el] = pb;
    }
    __syncthreads();
    #pragma unroll
    for (int kk = 0; kk < 2; ++kk) {
      bfrag a[4], b[4];
      #pragma unroll
      for (int m = 0; m < 4; ++m) {
        int r = wr + m * 16 + (lane & 15);
        int el = (r * 64 + kk * 32 + (lane >> 4) * 8) ^ ((r & 7) << 3);
        a[m] = *(const bfrag*)&As[el];
      }
      #pragma unroll
      for (int n = 0; n < 4; ++n) {
        int r = wc + n * 16 + (lane & 15);
        int el = (r * 64 + kk * 32 + (lane >> 4) * 8) ^ ((r & 7) << 3);
        b[n] = *(const bfrag*)&Bd[el];
      }
      #pragma unroll
      for (int m = 0; m < 4; ++m)
        #pragma unroll
        for (int n = 0; n < 4; ++n)
          acc[m][n] = __builtin_amdgcn_mfma_f32_16x16x32_bf16(a[m], b[n], acc[m][n], 0, 0, 0);
    }
  }

  #pragma unroll
  for (int m = 0; m < 4; ++m) {
    #pragma unroll
    for (int r4 = 0; r4 < 4; ++r4) {
      int rloc = wr + m * 16 + (lane >> 4) * 4 + r4;
      int grow = row0 + rloc;
      if (grow < nt) {
        int tok = toks[rloc];
        size_t base = (size_t)tok * H_DIM + h0 + wc + (lane & 15);
        #pragma unroll
        for (int n = 0; n < 4; ++n)
          atomicAdd(out + base + n * 16, acc[m][n][r4]);
      }
    }
  }
}

// ---------------- launch ----------------
extern "C" void kernel_launch(void* const* d_in, const int* in_sizes, int n_in,
                              void* d_out, int out_size, void* d_ws, size_t ws_size,
                              hipStream_t stream) {
  const float* x  = (const float*)d_in[0];
  const float* wr = (const float*)d_in[1];
  const float* wg = (const float*)d_in[2];
  const float* wu = (const float*)d_in[3];
  const float* wd = (const float*)d_in[4];
  float* out = (float*)d_out;
  float* logits_out = out + (size_t)T_TOK * H_DIM;   // tuple order: (out, router_logits)

  const long long WELEM = (long long)E_EXP * I_DIM * H_DIM;   // 50,331,648 per weight
  const size_t WBYT = (size_t)WELEM * 2;                      // 100,663,296

  // precast layout
  const size_t XB_OFF  = 0;                          // 16,777,216
  const size_t WGB_OFF = 16777216;
  const size_t WUB_OFF = WGB_OFF + WBYT;
  const size_t WDB_OFF = WUB_OFF + WBYT;
  const size_t TOK_OFF = WDB_OFF + WBYT;             // 318,767,104
  const size_t WGT_OFF = TOK_OFF + 524288;
  const size_t CNT_OFF = WGT_OFF + 524288;
  const size_t AOF_OFF = CNT_OFF + 256;
  const size_t ACT_OFF = AOF_OFF + 256;
  const size_t NEED    = ACT_OFF + (size_t)TOTAL_ROWS * I_DIM * 2;  // ~370.1 MB

  char* ws = (char*)d_ws;
  hipMemsetAsync(out, 0, (size_t)T_TOK * H_DIM * sizeof(float), stream);

  if (ws_size >= NEED) {
    unsigned short* xb  = (unsigned short*)(ws + XB_OFF);
    unsigned short* wgb = (unsigned short*)(ws + WGB_OFF);
    unsigned short* wub = (unsigned short*)(ws + WUB_OFF);
    unsigned short* wdb = (unsigned short*)(ws + WDB_OFF);
    int*   tok_list = (int*)(ws + TOK_OFF);
    float* wgt_list = (float*)(ws + WGT_OFF);
    int*   cnt  = (int*)(ws + CNT_OFF);
    int*   aoff = (int*)(ws + AOF_OFF);
    unsigned short* act = (unsigned short*)(ws + ACT_OFF);

    hipMemsetAsync(cnt, 0, 256, stream);
    cast_f32_bf16_kernel<<<4096, 256, 0, stream>>>(x, xb, (long long)T_TOK * H_DIM / 8);
    cast_f32_bf16_kernel<<<24576, 256, 0, stream>>>(wg, wgb, WELEM / 8);
    cast_f32_bf16_kernel<<<24576, 256, 0, stream>>>(wu, wub, WELEM / 8);
    cast_f32_bf16_kernel<<<24576, 256, 0, stream>>>(wd, wdb, WELEM / 8);
    router_kernel<<<T_TOK / 4, 256, 0, stream>>>(x, wr, logits_out, tok_list, wgt_list, cnt);
    scan_kernel<<<1, 64, 0, stream>>>(cnt, aoff);
    gateup_kernel<<<E_EXP * 32 * 6, 256, 0, stream>>>(
        xb, wgb, wub, cnt, aoff, tok_list, wgt_list, act);
    down_kernel<<<E_EXP * 32 * 16, 256, 0, stream>>>(
        act, wdb, cnt, aoff, tok_list, out);
  } else {
    // round-1 layout + kernels (proven PASS)
    unsigned short* xb   = (unsigned short*)ws;
    int*   tok_list      = (int*)(ws + 16777216);
    float* wgt_list      = (float*)(ws + 16777216 + 524288);
    int*   cnt           = (int*)(ws + 16777216 + 1048576);
    int*   aoff          = (int*)(ws + 16777216 + 1048576 + 256);
    unsigned short* act  = (unsigned short*)(ws + 16777216 + 1048576 + 512);

    hipMemsetAsync(cnt, 0, 256, stream);
    cast_f32_bf16_kernel<<<4096, 256, 0, stream>>>(x, xb, (long long)T_TOK * H_DIM / 8);
    router_kernel<<<T_TOK / 4, 256, 0, stream>>>(x, wr, logits_out, tok_list, wgt_list, cnt);
    scan_kernel<<<1, 64, 0, stream>>>(cnt, aoff);
    gateup_fb<<<dim3(E_EXP * 32, I_DIM / 128), 256, 0, stream>>>(
        xb, wg, wu, cnt, aoff, tok_list, wgt_list, act);
    down_fb<<<dim3(E_EXP * 32, H_DIM / 128), 256, 0, stream>>>(
        act, wd, cnt, aoff, tok_list, out);
  }
}